// Round 16
// baseline (2218.374 us; speedup 1.0000x reference)
//
#include <hip/hip_runtime.h>
#include <hip/hip_bf16.h>
#include <stdint.h>
#include <stddef.h>

#define R_ 64
#define C_ 256
#define E_ 768
#define H_ 12
#define F_ 3072
#define D_ 64
#define NT_ (R_*C_)   // 16384 tokens
#define HCRD_ ((size_t)H_*C_*R_*D_)

typedef float f32x4 __attribute__((ext_vector_type(4)));
typedef __bf16 bf16x8 __attribute__((ext_vector_type(8)));
typedef unsigned short us4 __attribute__((ext_vector_type(4)));
typedef unsigned short us8 __attribute__((ext_vector_type(8)));

typedef __attribute__((address_space(3))) uint32_t lds_u32;
typedef __attribute__((address_space(1))) uint32_t glb_u32;

__device__ __forceinline__ void gld16(const uint16_t* g, uint16_t* l) {
  __builtin_amdgcn_global_load_lds((const glb_u32*)g, (lds_u32*)l, 16, 0, 0);
}

__device__ __forceinline__ uint16_t f2b(float f) { // fp32 -> bf16, native cvt (RNE)
  __bf16 h = (__bf16)f;
  return *(uint16_t*)&h;
}

#define BAR      { asm volatile("s_barrier" ::: "memory"); }
#define VMW0     { asm volatile("s_waitcnt vmcnt(0)" ::: "memory"); }

enum { EP_F32B = 0, EP_GELU = 1, EP_AW = 2, EP_CTX = 3, EP_QKVROW = 4, EP_QKVCOL = 5 };

// ================================================================ 128x256 GEMM, BK=32 (all EPs)
// r14 structure with LDS cut to 48KB -> THREE blocks/CU co-resident (m114 latency
// absorption, the one lever that measurably moved this kernel: 1->2 blocks = +7%).
// K-loop: A 8KB x2 + B 16KB x2 = 48KB. Epilogue: 4 slabs of 8KB time-shared in the dead
// B region (waves 0-3 -> barrier -> waves 4-7). B stays in LDS (r15 lesson: LDS is the
// coalescing transposer; per-lane strided B loads gather-serialize in the TA).
template<int EP, bool PERM>
__global__ __launch_bounds__(512, 6)
void gemm128(const uint16_t* __restrict__ A, const uint16_t* __restrict__ B,
             const float* __restrict__ bias, const float* __restrict__ biasK,
             const float* __restrict__ biasV, void* __restrict__ out,
             int N, int K, int lda, int ldb, float scale)
{
  __shared__ uint16_t lds[24576];   // 48KB
  const int tid  = threadIdx.x;
  const int wave = tid >> 6, lane = tid & 63;
  const int wm = wave >> 2, wn = wave & 3;
  const int lr = lane & 15, lq = lane >> 4;

  // XCD-chunked bijective block swizzle (total blocks %8==0 in all uses)
  const int lin = blockIdx.x + gridDim.x * blockIdx.y;
  const int q8 = (gridDim.x * gridDim.y) >> 3;
  const int wid = (lin & 7) * q8 + (lin >> 3);
  const int bx = wid % gridDim.x, by = wid / gridDim.x;
  const long bm = (long)by * 128, bn = (long)bx * 256;

  // staging: A 8KB/tile (512 slots, 1/thread), B 16KB/tile (1024 slots, 2/thread)
  const int r0 = tid >> 2;                                 // 0..127
  const int c8 = (((tid & 3) ^ ((r0 >> 1) & 3)) << 3);     // both-sides XOR swizzle
  long am = bm + r0;
  if constexpr (PERM) am = ((am & 63) << 8) | (am >> 6);   // token (m&63)*256 + m>>6
  const uint16_t* aS  = A + am * (long)lda + c8;
  const uint16_t* bS0 = B + (bn + r0) * (long)ldb + c8;
  const uint16_t* bS1 = B + (bn + r0 + 128) * (long)ldb + c8;

  auto stage = [&](int u) {   // 3 gld16/thread per tile
    const int b = u & 1, kb = u << 5;
    gld16(aS  + kb, &lds[b * 4096 + tid * 8]);
    gld16(bS0 + kb, &lds[8192 + b * 8192 + tid * 8]);
    gld16(bS1 + kb, &lds[8192 + b * 8192 + (tid + 512) * 8]);
  };
  auto rdoff = [&](int row) { return row * 32 + ((lq ^ ((row >> 1) & 3)) << 3); };

  f32x4 acc[4][4];
#pragma unroll
  for (int i = 0; i < 4; ++i)
#pragma unroll
    for (int j = 0; j < 4; ++j) acc[i][j] = (f32x4){0.f, 0.f, 0.f, 0.f};

  const int nt = K >> 5;   // 24 or 96
  stage(0);
  VMW0; BAR;

  for (int t = 0; t < nt; ++t) {
    const int b = t & 1;
    if (t + 1 < nt) stage(t + 1);
    const uint16_t* Ab = &lds[b * 4096];
    const uint16_t* Bb = &lds[8192 + b * 8192];
    bf16x8 af[4], bf[4];
#pragma unroll
    for (int i = 0; i < 4; ++i) {
      af[i] = *(const bf16x8*)&Ab[rdoff(wm * 64 + i * 16 + lr)];
      bf[i] = *(const bf16x8*)&Bb[rdoff(wn * 64 + i * 16 + lr)];
    }
#pragma unroll
    for (int mi = 0; mi < 4; ++mi)
#pragma unroll
      for (int ni = 0; ni < 4; ++ni)
        acc[mi][ni] = __builtin_amdgcn_mfma_f32_16x16x32_bf16(af[mi], bf[ni], acc[mi][ni], 0, 0, 0);
    if (t + 1 < nt) { VMW0; BAR; }
  }
  __syncthreads();

  // ------------------------------------------------------------- epilogue (one 64x64/wave)
  if constexpr (EP == EP_F32B) {
#pragma unroll
    for (int mi = 0; mi < 4; ++mi)
#pragma unroll
      for (int ni = 0; ni < 4; ++ni)
#pragma unroll
        for (int r = 0; r < 4; ++r) {
          const long row = bm + wm * 64 + mi * 16 + lq * 4 + r;
          const long col = bn + wn * 64 + ni * 16 + lr;
          ((float*)out)[row * N + col] = acc[mi][ni][r] + bias[col];
        }
  } else {
    // 4 slabs of 8KB in the dead B region; waves 0-3 then waves 4-7 (time-shared)
    auto epilogue = [&]() {
      uint16_t* slab = &lds[8192 + (wave & 3) * 4096];   // wave-group-private 8KB
      const long colb = bn + wn * 64;
      const long m0 = bm + wm * 64;
      int grp = 0; long cc0 = colb;
      const float* bb = bias;
      if constexpr (EP != EP_GELU) {
        grp = colb >= 1536 ? 2 : (colb >= 768 ? 1 : 0);
        cc0 = colb - (long)grp * 768;
        bb = grp == 0 ? bias : (grp == 1 ? biasK : biasV);
      }
      const bool tr = (EP != EP_GELU) && (grp == 2);   // V dumps transposed [d][tok]
#pragma unroll
      for (int mi = 0; mi < 4; ++mi)
#pragma unroll
        for (int ni = 0; ni < 4; ++ni)
#pragma unroll
          for (int r = 0; r < 4; ++r) {
            const int lrow = mi * 16 + lq * 4 + r;
            const int lcol = ni * 16 + lr;
            float val;
            if constexpr (EP == EP_GELU) {
              const float t = acc[mi][ni][r] + bias[colb + lcol];
              const float u = 0.7978845608028654f * (t + 0.044715f * t * t * t);
              const float e2 = __expf(2.f * u);
              val = 0.5f * t * (2.f - 2.f / (e2 + 1.f));
            } else {
              val = acc[mi][ni][r] + bb[cc0 + lcol];
              if (grp == 0) val *= scale;
            }
            const int sr = tr ? lcol : lrow;
            const int sc = tr ? lrow : lcol;
            const int psc = (sc & 7) | ((((sc >> 3) ^ (sr & 7))) << 3);
            slab[sr * 64 + psc] = f2b(val);
          }
      // wave-private slab: ds_write -> ds_read same wave, no barrier needed
      uint16_t* o16 = (uint16_t*)out;
      long obase, rstride;
      if constexpr (EP == EP_GELU) {
        obase = m0 * (long)N + colb; rstride = N;
      } else {
        const long h = cc0 >> 6;
        if constexpr (EP == EP_QKVROW) {   // tile rows = tokens (fixed r, c varies)
          const long rr2 = m0 >> 8, c0 = m0 & 255;
          if (grp < 2) { obase = (size_t)grp * HCRD_ + ((h * C_ + c0) * R_ + rr2) * D_; rstride = R_ * D_; }
          else         { obase = 2 * HCRD_ + ((h * R_ + rr2) * D_) * C_ + c0;           rstride = C_; }
        } else {                           // QKVCOL: tile rows = r (fixed c)
          const long cq = m0 >> 6;
          if (grp < 2) { obase = (size_t)grp * HCRD_ + ((h * C_ + cq) * R_) * D_; rstride = D_; }
          else         { obase = 2 * HCRD_ + ((h * C_ + cq) * D_) * R_;           rstride = R_; }
        }
      }
      const int rl = lane >> 3, chn = lane & 7;
#pragma unroll
      for (int pp = 0; pp < 8; ++pp) {
        const int srow = pp * 8 + rl;
        const int pch = chn ^ (srow & 7);
        us8 wv = *(const us8*)&slab[srow * 64 + pch * 8];
        *(us8*)(o16 + obase + (long)srow * rstride + chn * 8) = wv;
      }
    };
    if (wave < 4) epilogue();
    __syncthreads();
    if (wave >= 4) epilogue();
  }
}

// ================================================================ 128x128 GEMM (AW / CTX)
template<int EP>
__global__ __launch_bounds__(256)
void gemm_bt(const uint16_t* __restrict__ A, const uint16_t* __restrict__ B,
             void* __restrict__ out,
             int M, int N, int K, int lda, int ldb, long sAz, long sBz)
{
  __shared__ uint16_t As[2][4096];
  __shared__ uint16_t Bs[2][4096];
  const int tid  = threadIdx.x;
  const int wave = tid >> 6, lane = tid & 63;
  const int z = blockIdx.z;

  const long bm = (long)blockIdx.y * 128;
  int kc = 0; long bnb = blockIdx.x;
  if constexpr (EP == EP_AW) { kc = blockIdx.x & 3; bnb = blockIdx.x >> 2; }
  const long bn = bnb * 128;
  const int wr = (wave >> 1) * 64;
  const int wc = (wave & 1) * 64;
  const int lr = lane & 15;
  const int lq = lane >> 4;

  const int t0 = tid, t1 = tid + 256;
  const int ar0 = t0 >> 2, ar1 = t1 >> 2;
  const int ac0 = (((t0 & 3) ^ ((ar0 >> 1) & 3)) * 8);
  const int ac1 = (((t1 & 3) ^ ((ar1 >> 1) & 3)) * 8);

  const uint16_t* a0p = A + (long)z * sAz + (bm + ar0) * (long)lda + (long)kc * 1024;
  const uint16_t* a1p = A + (long)z * sAz + (bm + ar1) * (long)lda + (long)kc * 1024;
  const uint16_t* b0p = B + (long)z * sBz + (bn + ar0) * (long)ldb + (long)kc * 1024;
  const uint16_t* b1p = B + (long)z * sBz + (bn + ar1) * (long)ldb + (long)kc * 1024;

  auto STAGE = [&](int bi, int kt) {
    gld16(a0p + kt + ac0, &As[bi][t0 * 8]);
    gld16(a1p + kt + ac1, &As[bi][t1 * 8]);
    gld16(b0p + kt + ac0, &Bs[bi][t0 * 8]);
    gld16(b1p + kt + ac1, &Bs[bi][t1 * 8]);
  };

  int apos[4], bpos[4];
#pragma unroll
  for (int i = 0; i < 4; ++i) {
    const int ra = wr + i * 16 + lr;
    const int rb = wc + i * 16 + lr;
    apos[i] = ra * 32 + (lq ^ ((ra >> 1) & 3)) * 8;
    bpos[i] = rb * 32 + (lq ^ ((rb >> 1) & 3)) * 8;
  }

  f32x4 acc[4][4];
#pragma unroll
  for (int i = 0; i < 4; ++i)
#pragma unroll
    for (int j = 0; j < 4; ++j) acc[i][j] = (f32x4){0.f, 0.f, 0.f, 0.f};

  const int nt = K >> 5;
  STAGE(0, 0);
  VMW0; BAR;

  for (int t = 0; t < nt; ++t) {
    const int b = t & 1;
    if (t + 1 < nt) STAGE(b ^ 1, (t + 1) << 5);
    bf16x8 af[4], bfm[4];
#pragma unroll
    for (int i = 0; i < 4; ++i) {
      af[i]  = *(const bf16x8*)&As[b][apos[i]];
      bfm[i] = *(const bf16x8*)&Bs[b][bpos[i]];
    }
#pragma unroll
    for (int mi = 0; mi < 4; ++mi)
#pragma unroll
      for (int ni = 0; ni < 4; ++ni)
        acc[mi][ni] = __builtin_amdgcn_mfma_f32_16x16x32_bf16(af[mi], bfm[ni], acc[mi][ni], 0, 0, 0);
    if (t + 1 < nt) { VMW0; BAR; }
  }

#pragma unroll
  for (int mi = 0; mi < 4; ++mi)
#pragma unroll
    for (int ni = 0; ni < 4; ++ni)
#pragma unroll
      for (int r = 0; r < 4; ++r) {
        const long row = bm + wr + mi * 16 + lq * 4 + r;
        const long col = bn + wc + ni * 16 + lr;
        if constexpr (EP == EP_AW) {
          ((float*)out)[((long)(z * 4 + kc) * M + row) * N + col] = acc[mi][ni][r];
        } else {  // EP_CTX
          ((uint16_t*)out)[((col >> 6) * C_ + row) * E_ + (long)z * 64 + (col & 63)] =
              f2b(acc[mi][ni][r]);
        }
      }
}

// ---------------------------------------------------------------- LayerNorm (fp32 in -> bf16 out)
__global__ __launch_bounds__(256)
void ln_k(const float* __restrict__ x, const float* __restrict__ s, const float* __restrict__ b,
          uint16_t* __restrict__ out)
{
  const int wave = threadIdx.x >> 6, lane = threadIdx.x & 63;
  const long row = (long)blockIdx.x * 4 + wave;
  const float* xr = x + row * E_;
  f32x4 v[3];
  float sum = 0.f, sq = 0.f;
#pragma unroll
  for (int i = 0; i < 3; ++i) {
    v[i] = *(const f32x4*)(xr + (i * 64 + lane) * 4);
#pragma unroll
    for (int j = 0; j < 4; ++j) { sum += v[i][j]; sq += v[i][j] * v[i][j]; }
  }
#pragma unroll
  for (int m = 1; m < 64; m <<= 1) { sum += __shfl_xor(sum, m); sq += __shfl_xor(sq, m); }
  const float mu = sum * (1.f / E_);
  const float var = sq * (1.f / E_) - mu * mu;
  const float rs = rsqrtf(var + 1e-6f);
  uint16_t* orow = out + row * E_;
#pragma unroll
  for (int i = 0; i < 3; ++i) {
    const int e0 = (i * 64 + lane) * 4;
    us4 o;
#pragma unroll
    for (int j = 0; j < 4; ++j) o[j] = f2b((v[i][j] - mu) * rs * s[e0 + j] + b[e0 + j]);
    *(us4*)(orow + e0) = o;
  }
}

// ------------------------------------------------ softmax over 256, summing 4 split-K partials
__global__ __launch_bounds__(256)
void softmax_k4(const float* __restrict__ aw4, uint16_t* __restrict__ ap)
{
  const int wave = threadIdx.x >> 6, lane = threadIdx.x & 63;
  const long row = (long)blockIdx.x * 4 + wave;
  const long h = row >> 8, i = row & 255;
  f32x4 v = (f32x4){0.f, 0.f, 0.f, 0.f};
#pragma unroll
  for (int kc = 0; kc < 4; ++kc) {
    f32x4 t = *(const f32x4*)(aw4 + (((h * 4 + kc) * C_ + i) * C_) + lane * 4);
#pragma unroll
    for (int j = 0; j < 4; ++j) v[j] += t[j];
  }
  float m = fmaxf(fmaxf(v[0], v[1]), fmaxf(v[2], v[3]));
#pragma unroll
  for (int k = 1; k < 64; k <<= 1) m = fmaxf(m, __shfl_xor(m, k));
  f32x4 e; float s = 0.f;
#pragma unroll
  for (int j = 0; j < 4; ++j) { e[j] = __expf(v[j] - m); s += e[j]; }
#pragma unroll
  for (int k = 1; k < 64; k <<= 1) s += __shfl_xor(s, k);
  const float inv = 1.f / s;
  us4 o;
#pragma unroll
  for (int j = 0; j < 4; ++j) o[j] = f2b(e[j] * inv);
  *(us4*)(ap + row * C_ + lane * 4) = o;
}

// ------------------------------------- weight transpose fp32->bf16: single (K,N)->(N,K) kernel
__global__ __launch_bounds__(256)
void tcvt(const float* __restrict__ in, uint16_t* __restrict__ out, int K, int N)
{
  __shared__ float t[32][33];
  const int tx = threadIdx.x, ty = threadIdx.y;   // block (32,8)
  const long k0 = (long)blockIdx.y * 32, n0 = (long)blockIdx.x * 32;
  for (int i = ty; i < 32; i += 8) t[i][tx] = in[(k0 + i) * N + n0 + tx];
  __syncthreads();
  for (int i = ty; i < 32; i += 8) out[(n0 + i) * K + k0 + tx] = f2b(t[tx][i]);
}

// ---------------------- batched 768x768 transpose for the 8 E x E weights (1 launch, z=0..7)
__global__ __launch_bounds__(256)
void tcvt8(const float* a0, const float* a1, const float* a2, const float* a3,
           const float* a4, const float* a5, const float* a6, const float* a7,
           uint16_t* o0, uint16_t* o1, uint16_t* o2, uint16_t* o3,
           uint16_t* o4, uint16_t* o5, uint16_t* o6, uint16_t* o7)
{
  __shared__ float t[32][33];
  const float* in; uint16_t* out;
  switch (blockIdx.z) {
    case 0: in = a0; out = o0; break;
    case 1: in = a1; out = o1; break;
    case 2: in = a2; out = o2; break;
    case 3: in = a3; out = o3; break;
    case 4: in = a4; out = o4; break;
    case 5: in = a5; out = o5; break;
    case 6: in = a6; out = o6; break;
    default: in = a7; out = o7; break;
  }
  const int tx = threadIdx.x, ty = threadIdx.y;   // block (32,8)
  const long k0 = (long)blockIdx.y * 32, n0 = (long)blockIdx.x * 32;
  for (int i = ty; i < 32; i += 8) t[i][tx] = in[(k0 + i) * E_ + n0 + tx];
  __syncthreads();
  for (int i = ty; i < 32; i += 8) out[(n0 + i) * E_ + k0 + tx] = f2b(t[tx][i]);
}

// ---------------------------------------------------------------- fused column attention
__global__ __launch_bounds__(64)
void colattn(const uint16_t* __restrict__ q, const uint16_t* __restrict__ k,
             const uint16_t* __restrict__ v, uint16_t* __restrict__ ctx)
{
  __shared__ uint16_t Qs[64 * 64];
  __shared__ uint16_t Ks[64 * 64];
  __shared__ uint16_t Vs[64 * 64];
  const int hc = blockIdx.x;
  const int h = hc >> 8, c = hc & 255;
  const int lane = threadIdx.x;
  const uint16_t* qb = q + (long)hc * (R_ * D_);
  const uint16_t* kb = k + (long)hc * (R_ * D_);
  const uint16_t* vb = v + (long)hc * (D_ * R_);
#pragma unroll
  for (int it = 0; it < 8; ++it) {
    const int o = (it * 64 + lane) * 8;
    gld16(qb + o, &Qs[o]);
    gld16(kb + o, &Ks[o]);
    gld16(vb + o, &Vs[o]);
  }
  asm volatile("s_waitcnt vmcnt(0)" ::: "memory");
  __builtin_amdgcn_sched_barrier(0);

  const int lr = lane & 15, lq = lane >> 4;
  f32x4 acc[4][4];
#pragma unroll
  for (int i = 0; i < 4; ++i)
#pragma unroll
    for (int j = 0; j < 4; ++j) acc[i][j] = (f32x4){0.f, 0.f, 0.f, 0.f};

#pragma unroll
  for (int kt = 0; kt < 2; ++kt) {
    bf16x8 af[4], bfm[4];
#pragma unroll
    for (int i = 0; i < 4; ++i) {
      af[i]  = *(const bf16x8*)&Qs[(i * 16 + lr) * 64 + kt * 32 + lq * 8];
      bfm[i] = *(const bf16x8*)&Ks[(i * 16 + lr) * 64 + kt * 32 + lq * 8];
    }
#pragma unroll
    for (int mi = 0; mi < 4; ++mi)
#pragma unroll
      for (int ni = 0; ni < 4; ++ni)
        acc[mi][ni] = __builtin_amdgcn_mfma_f32_16x16x32_bf16(af[mi], bfm[ni], acc[mi][ni], 0, 0, 0);
  }

#pragma unroll
  for (int mi = 0; mi < 4; ++mi) {
#pragma unroll
    for (int r = 0; r < 4; ++r) {
      float mx = fmaxf(fmaxf(acc[mi][0][r], acc[mi][1][r]), fmaxf(acc[mi][2][r], acc[mi][3][r]));
#pragma unroll
      for (int s = 1; s < 16; s <<= 1) mx = fmaxf(mx, __shfl_xor(mx, s));
      float e0 = __expf(acc[mi][0][r] - mx), e1 = __expf(acc[mi][1][r] - mx);
      float e2 = __expf(acc[mi][2][r] - mx), e3 = __expf(acc[mi][3][r] - mx);
      float sum = e0 + e1 + e2 + e3;
#pragma unroll
      for (int s = 1; s < 16; s <<= 1) sum += __shfl_xor(sum, s);
      const float inv = 1.f / sum;
      const int i = mi * 16 + lq * 4 + r;
      Qs[i * 64 +  0 + lr] = f2b(e0 * inv);
      Qs[i * 64 + 16 + lr] = f2b(e1 * inv);
      Qs[i * 64 + 32 + lr] = f2b(e2 * inv);
      Qs[i * 64 + 48 + lr] = f2b(e3 * inv);
    }
  }
  __syncthreads();

  f32x4 o_[4][4];
#pragma unroll
  for (int i = 0; i < 4; ++i)
#pragma unroll
    for (int j = 0; j < 4; ++j) o_[i][j] = (f32x4){0.f, 0.f, 0.f, 0.f};

#pragma unroll
  for (int kt = 0; kt < 2; ++kt) {
    bf16x8 pa[4], vv[4];
#pragma unroll
    for (int i = 0; i < 4; ++i) {
      pa[i] = *(const bf16x8*)&Qs[(i * 16 + lr) * 64 + kt * 32 + lq * 8];
      vv[i] = *(const bf16x8*)&Vs[(i * 16 + lr) * 64 + kt * 32 + lq * 8];
    }
#pragma unroll
    for (int mi = 0; mi < 4; ++mi)
#pragma unroll
      for (int ni = 0; ni < 4; ++ni)
        o_[mi][ni] = __builtin_amdgcn_mfma_f32_16x16x32_bf16(pa[mi], vv[ni], o_[mi][ni], 0, 0, 0);
  }

#pragma unroll
  for (int mi = 0; mi < 4; ++mi)
#pragma unroll
    for (int ni = 0; ni < 4; ++ni)
#pragma unroll
      for (int r = 0; r < 4; ++r) {
        const int i = mi * 16 + lq * 4 + r;
        const int d = ni * 16 + lr;
        ctx[((long)i * C_ + c) * E_ + h * 64 + d] = f2b(o_[mi][ni][r]);
      }
}

// ---------------------------------------------------------------- host launch
extern "C" void kernel_launch(void* const* d_in, const int* in_sizes, int n_in,
                              void* d_out, int out_size, void* d_ws, size_t ws_size,
                              hipStream_t stream)
{
  (void)in_sizes; (void)n_in; (void)out_size; (void)ws_size;
  const float* x     = (const float*)d_in[0];
  const float* ln1_s = (const float*)d_in[1];
  const float* ln1_b = (const float*)d_in[2];
  const float* r_wq  = (const float*)d_in[3];
  const float* r_bq  = (const float*)d_in[4];
  const float* r_wk  = (const float*)d_in[5];
  const float* r_bk  = (const float*)d_in[6];
  const float* r_wv  = (const float*)d_in[7];
  const float* r_bv  = (const float*)d_in[8];
  const float* r_wo  = (const float*)d_in[9];
  const float* r_bo  = (const float*)d_in[10];
  const float* ln2_s = (const float*)d_in[11];
  const float* ln2_b = (const float*)d_in[12];
  const float* c_wq  = (const float*)d_in[13];
  const float* c_bq  = (const float*)d_in[14];
  const float* c_wk  = (const float*)d_in[15];
  const float* c_bk  = (const float*)d_in[16];
  const float* c_wv  = (const float*)d_in[17];
  const float* c_bv  = (const float*)d_in[18];
  const float* c_wo  = (const float*)d_in[19];
  const float* c_bo  = (const float*)d_in[20];
  const float* ln3_s = (const float*)d_in[21];
  const float* ln3_b = (const float*)d_in[22];
  const float* f_w1  = (const float*)d_in[23];
  const float* f_b1  = (const float*)d_in[24];
  const float* f_w2  = (const float*)d_in[25];
  const float* f_b2  = (const float*)d_in[26];

  uint8_t* p = (uint8_t*)d_ws;
  auto take = [&p](size_t n) { uint8_t* r = p; p += (n + 255) & ~(size_t)255; return r; };

  uint16_t* wqkv1 = (uint16_t*)take((size_t)3 * E_ * E_ * 2);
  uint16_t* wqkv2 = (uint16_t*)take((size_t)3 * E_ * E_ * 2);
  uint16_t* rwoT  = (uint16_t*)take((size_t)E_ * E_ * 2);
  uint16_t* cwoT  = (uint16_t*)take((size_t)E_ * E_ * 2);
  uint16_t* w1T   = (uint16_t*)take((size_t)E_ * F_ * 2);
  uint16_t* w2T   = (uint16_t*)take((size_t)F_ * E_ * 2);
  uint16_t* hb    = (uint16_t*)take((size_t)NT_ * E_ * 2);
  uint16_t* qkvT  = (uint16_t*)take(3 * HCRD_ * 2);
  uint16_t* qT = qkvT, *kT = qkvT + HCRD_, *vT = qkvT + 2 * HCRD_;
  uint16_t* ctxb  = (uint16_t*)take((size_t)NT_ * E_ * 2);
  uint16_t* apb   = (uint16_t*)take((size_t)H_ * C_ * C_ * 2);
  uint16_t* g     = qkvT;          // alias: stage-3 FFN hidden over dead q/k/v
  float*    awb4  = (float*)ctxb;  // alias: split-K partials dead before ctxb written
  float*    x1    = (float*)d_out; // alias: inter-stage fp32 activation in output buf

  const dim3 tb32(32, 8);
  tcvt8<<<dim3(E_ / 32, E_ / 32, 8), tb32, 0, stream>>>(
      r_wq, r_wk, r_wv, c_wq, c_wk, c_wv, r_wo, c_wo,
      wqkv1 + 0 * E_ * E_, wqkv1 + 1 * E_ * E_, wqkv1 + 2 * E_ * E_,
      wqkv2 + 0 * E_ * E_, wqkv2 + 1 * E_ * E_, wqkv2 + 2 * E_ * E_,
      rwoT, cwoT);
  tcvt<<<dim3(F_ / 32, E_ / 32), tb32, 0, stream>>>(f_w1, w1T, E_, F_);
  tcvt<<<dim3(E_ / 32, F_ / 32), tb32, 0, stream>>>(f_w2, w2T, F_, E_);

  // ---- stage 1: tied-row attention ----
  ln_k<<<NT_ / 4, 256, 0, stream>>>(x, ln1_s, ln1_b, hb);
  gemm128<EP_QKVROW, false><<<dim3(9, 128), 512, 0, stream>>>(
      hb, wqkv1, r_bq, r_bk, r_bv, qkvT, 3 * E_, E_, E_, E_, 0.015625f);
  gemm_bt<EP_AW><<<dim3(8, 2, H_), 256, 0, stream>>>(
      qT, kT, awb4, C_, C_, 1024, R_ * D_, R_ * D_, (long)C_ * R_ * D_, (long)C_ * R_ * D_);
  softmax_k4<<<(H_ * C_) / 4, 256, 0, stream>>>(awb4, apb);
  gemm_bt<EP_CTX><<<dim3((R_ * D_) / 128, 2, H_), 256, 0, stream>>>(
      apb, vT, ctxb, C_, R_ * D_, C_, C_, C_, (long)C_ * C_, (long)R_ * D_ * C_);
  gemm128<EP_F32B, false><<<dim3(3, 128), 512, 0, stream>>>(
      ctxb, rwoT, r_bo, nullptr, nullptr, x1, E_, E_, E_, E_, 1.f);

  // ---- stage 2: column attention ----
  ln_k<<<NT_ / 4, 256, 0, stream>>>(x1, ln2_s, ln2_b, hb);
  gemm128<EP_QKVCOL, true><<<dim3(9, 128), 512, 0, stream>>>(
      hb, wqkv2, c_bq, c_bk, c_bv, qkvT, 3 * E_, E_, E_, E_, 0.125f);
  colattn<<<H_ * C_, 64, 0, stream>>>(qT, kT, vT, ctxb);
  gemm128<EP_F32B, false><<<dim3(3, 128), 512, 0, stream>>>(
      ctxb, cwoT, c_bo, nullptr, nullptr, x1, E_, E_, E_, E_, 1.f);

  // ---- stage 3: FFN ----
  ln_k<<<NT_ / 4, 256, 0, stream>>>(x1, ln3_s, ln3_b, hb);
  gemm128<EP_GELU, false><<<dim3(12, 128), 512, 0, stream>>>(
      hb, w1T, f_b1, nullptr, nullptr, g, F_, E_, E_, E_, 1.f);
  gemm128<EP_F32B, false><<<dim3(3, 128), 512, 0, stream>>>(
      g, w2T, f_b2, nullptr, nullptr, d_out, E_, F_, F_, F_, 1.f);
}

// Round 17
// 516.471 us; speedup vs baseline: 4.2953x; 4.2953x over previous
//
#include <hip/hip_runtime.h>
#include <hip/hip_bf16.h>
#include <stdint.h>
#include <stddef.h>

#define R_ 64
#define C_ 256
#define E_ 768
#define H_ 12
#define F_ 3072
#define D_ 64
#define NT_ (R_*C_)   // 16384 tokens
#define HCRD_ ((size_t)H_*C_*R_*D_)

typedef float f32x4 __attribute__((ext_vector_type(4)));
typedef __bf16 bf16x8 __attribute__((ext_vector_type(8)));
typedef unsigned short us4 __attribute__((ext_vector_type(4)));
typedef unsigned short us8 __attribute__((ext_vector_type(8)));

typedef __attribute__((address_space(3))) uint32_t lds_u32;
typedef __attribute__((address_space(1))) uint32_t glb_u32;

__device__ __forceinline__ void gld16(const uint16_t* g, uint16_t* l) {
  __builtin_amdgcn_global_load_lds((const glb_u32*)g, (lds_u32*)l, 16, 0, 0);
}

__device__ __forceinline__ uint16_t f2b(float f) { // fp32 -> bf16, native cvt (RNE)
  __bf16 h = (__bf16)f;
  return *(uint16_t*)&h;
}

#define BAR      { asm volatile("s_barrier" ::: "memory"); }
#define VMW0     { asm volatile("s_waitcnt vmcnt(0)" ::: "memory"); }

enum { EP_F32B = 0, EP_GELU = 1, EP_AW = 2, EP_CTX = 3, EP_QKVROW = 4, EP_QKVCOL = 5 };

// ================================================================ 128x256 GEMM, BK=32 (all EPs)
// Verified r14 operating point (519us total): 8 waves (2M x 4N), wave tile 64x64,
// acc[4][4] (VGPR 56, no spill) -> TWO blocks/CU co-resident (m114 latency absorption).
// LDS 64KB: K-loop uses 48KB (A 8KB x2 + B 16KB x2); epilogue slab 8 waves x 8KB.
template<int EP, bool PERM>
__global__ __launch_bounds__(512, 4)
void gemm128(const uint16_t* __restrict__ A, const uint16_t* __restrict__ B,
             const float* __restrict__ bias, const float* __restrict__ biasK,
             const float* __restrict__ biasV, void* __restrict__ out,
             int N, int K, int lda, int ldb, float scale)
{
  __shared__ uint16_t lds[32768];   // 64KB
  const int tid  = threadIdx.x;
  const int wave = tid >> 6, lane = tid & 63;
  const int wm = wave >> 2, wn = wave & 3;
  const int lr = lane & 15, lq = lane >> 4;

  // XCD-chunked bijective block swizzle (total blocks %8==0 in all uses)
  const int lin = blockIdx.x + gridDim.x * blockIdx.y;
  const int q8 = (gridDim.x * gridDim.y) >> 3;
  const int wid = (lin & 7) * q8 + (lin >> 3);
  const int bx = wid % gridDim.x, by = wid / gridDim.x;
  const long bm = (long)by * 128, bn = (long)bx * 256;

  // staging: A 8KB/tile (512 slots, 1/thread), B 16KB/tile (1024 slots, 2/thread)
  const int r0 = tid >> 2;                                 // 0..127
  const int c8 = (((tid & 3) ^ ((r0 >> 1) & 3)) << 3);     // both-sides XOR swizzle
  long am = bm + r0;
  if constexpr (PERM) am = ((am & 63) << 8) | (am >> 6);   // token (m&63)*256 + m>>6
  const uint16_t* aS  = A + am * (long)lda + c8;
  const uint16_t* bS0 = B + (bn + r0) * (long)ldb + c8;
  const uint16_t* bS1 = B + (bn + r0 + 128) * (long)ldb + c8;

  auto stage = [&](int u) {   // 3 gld16/thread per tile
    const int b = u & 1, kb = u << 5;
    gld16(aS  + kb, &lds[b * 4096 + tid * 8]);
    gld16(bS0 + kb, &lds[8192 + b * 8192 + tid * 8]);
    gld16(bS1 + kb, &lds[8192 + b * 8192 + (tid + 512) * 8]);
  };
  auto rdoff = [&](int row) { return row * 32 + ((lq ^ ((row >> 1) & 3)) << 3); };

  f32x4 acc[4][4];
#pragma unroll
  for (int i = 0; i < 4; ++i)
#pragma unroll
    for (int j = 0; j < 4; ++j) acc[i][j] = (f32x4){0.f, 0.f, 0.f, 0.f};

  const int nt = K >> 5;   // 24 or 96
  stage(0);
  VMW0; BAR;

  for (int t = 0; t < nt; ++t) {
    const int b = t & 1;
    if (t + 1 < nt) stage(t + 1);
    const uint16_t* Ab = &lds[b * 4096];
    const uint16_t* Bb = &lds[8192 + b * 8192];
    bf16x8 af[4], bf[4];
#pragma unroll
    for (int i = 0; i < 4; ++i) {
      af[i] = *(const bf16x8*)&Ab[rdoff(wm * 64 + i * 16 + lr)];
      bf[i] = *(const bf16x8*)&Bb[rdoff(wn * 64 + i * 16 + lr)];
    }
#pragma unroll
    for (int mi = 0; mi < 4; ++mi)
#pragma unroll
      for (int ni = 0; ni < 4; ++ni)
        acc[mi][ni] = __builtin_amdgcn_mfma_f32_16x16x32_bf16(af[mi], bf[ni], acc[mi][ni], 0, 0, 0);
    if (t + 1 < nt) { VMW0; BAR; }
  }
  __syncthreads();

  // ------------------------------------------------------------- epilogue (one 64x64/wave)
  if constexpr (EP == EP_F32B) {
#pragma unroll
    for (int mi = 0; mi < 4; ++mi)
#pragma unroll
      for (int ni = 0; ni < 4; ++ni)
#pragma unroll
        for (int r = 0; r < 4; ++r) {
          const long row = bm + wm * 64 + mi * 16 + lq * 4 + r;
          const long col = bn + wn * 64 + ni * 16 + lr;
          ((float*)out)[row * N + col] = acc[mi][ni][r] + bias[col];
        }
  } else {
    uint16_t* slab = &lds[wave * 4096];   // wave-private 8KB
    const long colb = bn + wn * 64;
    const long m0 = bm + wm * 64;
    int grp = 0; long cc0 = colb;
    const float* bb = bias;
    if constexpr (EP != EP_GELU) {
      grp = colb >= 1536 ? 2 : (colb >= 768 ? 1 : 0);
      cc0 = colb - (long)grp * 768;
      bb = grp == 0 ? bias : (grp == 1 ? biasK : biasV);
    }
    const bool tr = (EP != EP_GELU) && (grp == 2);   // V dumps transposed [d][tok]
#pragma unroll
    for (int mi = 0; mi < 4; ++mi)
#pragma unroll
      for (int ni = 0; ni < 4; ++ni)
#pragma unroll
        for (int r = 0; r < 4; ++r) {
          const int lrow = mi * 16 + lq * 4 + r;
          const int lcol = ni * 16 + lr;
          float val;
          if constexpr (EP == EP_GELU) {
            const float t = acc[mi][ni][r] + bias[colb + lcol];
            const float u = 0.7978845608028654f * (t + 0.044715f * t * t * t);
            const float e2 = __expf(2.f * u);
            val = 0.5f * t * (2.f - 2.f / (e2 + 1.f));
          } else {
            val = acc[mi][ni][r] + bb[cc0 + lcol];
            if (grp == 0) val *= scale;
          }
          const int sr = tr ? lcol : lrow;
          const int sc = tr ? lrow : lcol;
          const int psc = (sc & 7) | ((((sc >> 3) ^ (sr & 7))) << 3);
          slab[sr * 64 + psc] = f2b(val);
        }
    // wave-private slab: ds_write -> ds_read same wave, no barrier needed
    uint16_t* o16 = (uint16_t*)out;
    long obase, rstride;
    if constexpr (EP == EP_GELU) {
      obase = m0 * (long)N + colb; rstride = N;
    } else {
      const long h = cc0 >> 6;
      if constexpr (EP == EP_QKVROW) {   // tile rows = tokens (fixed r, c varies)
        const long rr2 = m0 >> 8, c0 = m0 & 255;
        if (grp < 2) { obase = (size_t)grp * HCRD_ + ((h * C_ + c0) * R_ + rr2) * D_; rstride = R_ * D_; }
        else         { obase = 2 * HCRD_ + ((h * R_ + rr2) * D_) * C_ + c0;           rstride = C_; }
      } else {                           // QKVCOL: tile rows = r (fixed c)
        const long cq = m0 >> 6;
        if (grp < 2) { obase = (size_t)grp * HCRD_ + ((h * C_ + cq) * R_) * D_; rstride = D_; }
        else         { obase = 2 * HCRD_ + ((h * C_ + cq) * D_) * R_;           rstride = R_; }
      }
    }
    const int rl = lane >> 3, chn = lane & 7;
#pragma unroll
    for (int pp = 0; pp < 8; ++pp) {
      const int srow = pp * 8 + rl;
      const int pch = chn ^ (srow & 7);
      us8 wv = *(const us8*)&slab[srow * 64 + pch * 8];
      *(us8*)(o16 + obase + (long)srow * rstride + chn * 8) = wv;
    }
  }
}

// ================================================================ 128x128 GEMM (AW / CTX)
template<int EP>
__global__ __launch_bounds__(256)
void gemm_bt(const uint16_t* __restrict__ A, const uint16_t* __restrict__ B,
             void* __restrict__ out,
             int M, int N, int K, int lda, int ldb, long sAz, long sBz)
{
  __shared__ uint16_t As[2][4096];
  __shared__ uint16_t Bs[2][4096];
  const int tid  = threadIdx.x;
  const int wave = tid >> 6, lane = tid & 63;
  const int z = blockIdx.z;

  const long bm = (long)blockIdx.y * 128;
  int kc = 0; long bnb = blockIdx.x;
  if constexpr (EP == EP_AW) { kc = blockIdx.x & 3; bnb = blockIdx.x >> 2; }
  const long bn = bnb * 128;
  const int wr = (wave >> 1) * 64;
  const int wc = (wave & 1) * 64;
  const int lr = lane & 15;
  const int lq = lane >> 4;

  const int t0 = tid, t1 = tid + 256;
  const int ar0 = t0 >> 2, ar1 = t1 >> 2;
  const int ac0 = (((t0 & 3) ^ ((ar0 >> 1) & 3)) * 8);
  const int ac1 = (((t1 & 3) ^ ((ar1 >> 1) & 3)) * 8);

  const uint16_t* a0p = A + (long)z * sAz + (bm + ar0) * (long)lda + (long)kc * 1024;
  const uint16_t* a1p = A + (long)z * sAz + (bm + ar1) * (long)lda + (long)kc * 1024;
  const uint16_t* b0p = B + (long)z * sBz + (bn + ar0) * (long)ldb + (long)kc * 1024;
  const uint16_t* b1p = B + (long)z * sBz + (bn + ar1) * (long)ldb + (long)kc * 1024;

  auto STAGE = [&](int bi, int kt) {
    gld16(a0p + kt + ac0, &As[bi][t0 * 8]);
    gld16(a1p + kt + ac1, &As[bi][t1 * 8]);
    gld16(b0p + kt + ac0, &Bs[bi][t0 * 8]);
    gld16(b1p + kt + ac1, &Bs[bi][t1 * 8]);
  };

  int apos[4], bpos[4];
#pragma unroll
  for (int i = 0; i < 4; ++i) {
    const int ra = wr + i * 16 + lr;
    const int rb = wc + i * 16 + lr;
    apos[i] = ra * 32 + (lq ^ ((ra >> 1) & 3)) * 8;
    bpos[i] = rb * 32 + (lq ^ ((rb >> 1) & 3)) * 8;
  }

  f32x4 acc[4][4];
#pragma unroll
  for (int i = 0; i < 4; ++i)
#pragma unroll
    for (int j = 0; j < 4; ++j) acc[i][j] = (f32x4){0.f, 0.f, 0.f, 0.f};

  const int nt = K >> 5;
  STAGE(0, 0);
  VMW0; BAR;

  for (int t = 0; t < nt; ++t) {
    const int b = t & 1;
    if (t + 1 < nt) STAGE(b ^ 1, (t + 1) << 5);
    bf16x8 af[4], bfm[4];
#pragma unroll
    for (int i = 0; i < 4; ++i) {
      af[i]  = *(const bf16x8*)&As[b][apos[i]];
      bfm[i] = *(const bf16x8*)&Bs[b][bpos[i]];
    }
#pragma unroll
    for (int mi = 0; mi < 4; ++mi)
#pragma unroll
      for (int ni = 0; ni < 4; ++ni)
        acc[mi][ni] = __builtin_amdgcn_mfma_f32_16x16x32_bf16(af[mi], bfm[ni], acc[mi][ni], 0, 0, 0);
    if (t + 1 < nt) { VMW0; BAR; }
  }

#pragma unroll
  for (int mi = 0; mi < 4; ++mi)
#pragma unroll
    for (int ni = 0; ni < 4; ++ni)
#pragma unroll
      for (int r = 0; r < 4; ++r) {
        const long row = bm + wr + mi * 16 + lq * 4 + r;
        const long col = bn + wc + ni * 16 + lr;
        if constexpr (EP == EP_AW) {
          ((float*)out)[((long)(z * 4 + kc) * M + row) * N + col] = acc[mi][ni][r];
        } else {  // EP_CTX
          ((uint16_t*)out)[((col >> 6) * C_ + row) * E_ + (long)z * 64 + (col & 63)] =
              f2b(acc[mi][ni][r]);
        }
      }
}

// ---------------------------------------------------------------- LayerNorm (fp32 in -> bf16 out)
__global__ __launch_bounds__(256)
void ln_k(const float* __restrict__ x, const float* __restrict__ s, const float* __restrict__ b,
          uint16_t* __restrict__ out)
{
  const int wave = threadIdx.x >> 6, lane = threadIdx.x & 63;
  const long row = (long)blockIdx.x * 4 + wave;
  const float* xr = x + row * E_;
  f32x4 v[3];
  float sum = 0.f, sq = 0.f;
#pragma unroll
  for (int i = 0; i < 3; ++i) {
    v[i] = *(const f32x4*)(xr + (i * 64 + lane) * 4);
#pragma unroll
    for (int j = 0; j < 4; ++j) { sum += v[i][j]; sq += v[i][j] * v[i][j]; }
  }
#pragma unroll
  for (int m = 1; m < 64; m <<= 1) { sum += __shfl_xor(sum, m); sq += __shfl_xor(sq, m); }
  const float mu = sum * (1.f / E_);
  const float var = sq * (1.f / E_) - mu * mu;
  const float rs = rsqrtf(var + 1e-6f);
  uint16_t* orow = out + row * E_;
#pragma unroll
  for (int i = 0; i < 3; ++i) {
    const int e0 = (i * 64 + lane) * 4;
    us4 o;
#pragma unroll
    for (int j = 0; j < 4; ++j) o[j] = f2b((v[i][j] - mu) * rs * s[e0 + j] + b[e0 + j]);
    *(us4*)(orow + e0) = o;
  }
}

// ------------------------------------------------ softmax over 256, summing 4 split-K partials
__global__ __launch_bounds__(256)
void softmax_k4(const float* __restrict__ aw4, uint16_t* __restrict__ ap)
{
  const int wave = threadIdx.x >> 6, lane = threadIdx.x & 63;
  const long row = (long)blockIdx.x * 4 + wave;
  const long h = row >> 8, i = row & 255;
  f32x4 v = (f32x4){0.f, 0.f, 0.f, 0.f};
#pragma unroll
  for (int kc = 0; kc < 4; ++kc) {
    f32x4 t = *(const f32x4*)(aw4 + (((h * 4 + kc) * C_ + i) * C_) + lane * 4);
#pragma unroll
    for (int j = 0; j < 4; ++j) v[j] += t[j];
  }
  float m = fmaxf(fmaxf(v[0], v[1]), fmaxf(v[2], v[3]));
#pragma unroll
  for (int k = 1; k < 64; k <<= 1) m = fmaxf(m, __shfl_xor(m, k));
  f32x4 e; float s = 0.f;
#pragma unroll
  for (int j = 0; j < 4; ++j) { e[j] = __expf(v[j] - m); s += e[j]; }
#pragma unroll
  for (int k = 1; k < 64; k <<= 1) s += __shfl_xor(s, k);
  const float inv = 1.f / s;
  us4 o;
#pragma unroll
  for (int j = 0; j < 4; ++j) o[j] = f2b(e[j] * inv);
  *(us4*)(ap + row * C_ + lane * 4) = o;
}

// ------------------------------------- weight transpose fp32->bf16: single (K,N)->(N,K) kernel
__global__ __launch_bounds__(256)
void tcvt(const float* __restrict__ in, uint16_t* __restrict__ out, int K, int N)
{
  __shared__ float t[32][33];
  const int tx = threadIdx.x, ty = threadIdx.y;   // block (32,8)
  const long k0 = (long)blockIdx.y * 32, n0 = (long)blockIdx.x * 32;
  for (int i = ty; i < 32; i += 8) t[i][tx] = in[(k0 + i) * N + n0 + tx];
  __syncthreads();
  for (int i = ty; i < 32; i += 8) out[(n0 + i) * K + k0 + tx] = f2b(t[tx][i]);
}

// ---------------------- batched 768x768 transpose for the 8 E x E weights (1 launch, z=0..7)
__global__ __launch_bounds__(256)
void tcvt8(const float* a0, const float* a1, const float* a2, const float* a3,
           const float* a4, const float* a5, const float* a6, const float* a7,
           uint16_t* o0, uint16_t* o1, uint16_t* o2, uint16_t* o3,
           uint16_t* o4, uint16_t* o5, uint16_t* o6, uint16_t* o7)
{
  __shared__ float t[32][33];
  const float* in; uint16_t* out;
  switch (blockIdx.z) {
    case 0: in = a0; out = o0; break;
    case 1: in = a1; out = o1; break;
    case 2: in = a2; out = o2; break;
    case 3: in = a3; out = o3; break;
    case 4: in = a4; out = o4; break;
    case 5: in = a5; out = o5; break;
    case 6: in = a6; out = o6; break;
    default: in = a7; out = o7; break;
  }
  const int tx = threadIdx.x, ty = threadIdx.y;   // block (32,8)
  const long k0 = (long)blockIdx.y * 32, n0 = (long)blockIdx.x * 32;
  for (int i = ty; i < 32; i += 8) t[i][tx] = in[(k0 + i) * E_ + n0 + tx];
  __syncthreads();
  for (int i = ty; i < 32; i += 8) out[(n0 + i) * E_ + k0 + tx] = f2b(t[tx][i]);
}

// ---------------------------------------------------------------- fused column attention
__global__ __launch_bounds__(64)
void colattn(const uint16_t* __restrict__ q, const uint16_t* __restrict__ k,
             const uint16_t* __restrict__ v, uint16_t* __restrict__ ctx)
{
  __shared__ uint16_t Qs[64 * 64];
  __shared__ uint16_t Ks[64 * 64];
  __shared__ uint16_t Vs[64 * 64];
  const int hc = blockIdx.x;
  const int h = hc >> 8, c = hc & 255;
  const int lane = threadIdx.x;
  const uint16_t* qb = q + (long)hc * (R_ * D_);
  const uint16_t* kb = k + (long)hc * (R_ * D_);
  const uint16_t* vb = v + (long)hc * (D_ * R_);
#pragma unroll
  for (int it = 0; it < 8; ++it) {
    const int o = (it * 64 + lane) * 8;
    gld16(qb + o, &Qs[o]);
    gld16(kb + o, &Ks[o]);
    gld16(vb + o, &Vs[o]);
  }
  asm volatile("s_waitcnt vmcnt(0)" ::: "memory");
  __builtin_amdgcn_sched_barrier(0);

  const int lr = lane & 15, lq = lane >> 4;
  f32x4 acc[4][4];
#pragma unroll
  for (int i = 0; i < 4; ++i)
#pragma unroll
    for (int j = 0; j < 4; ++j) acc[i][j] = (f32x4){0.f, 0.f, 0.f, 0.f};

#pragma unroll
  for (int kt = 0; kt < 2; ++kt) {
    bf16x8 af[4], bfm[4];
#pragma unroll
    for (int i = 0; i < 4; ++i) {
      af[i]  = *(const bf16x8*)&Qs[(i * 16 + lr) * 64 + kt * 32 + lq * 8];
      bfm[i] = *(const bf16x8*)&Ks[(i * 16 + lr) * 64 + kt * 32 + lq * 8];
    }
#pragma unroll
    for (int mi = 0; mi < 4; ++mi)
#pragma unroll
      for (int ni = 0; ni < 4; ++ni)
        acc[mi][ni] = __builtin_amdgcn_mfma_f32_16x16x32_bf16(af[mi], bfm[ni], acc[mi][ni], 0, 0, 0);
  }

#pragma unroll
  for (int mi = 0; mi < 4; ++mi) {
#pragma unroll
    for (int r = 0; r < 4; ++r) {
      float mx = fmaxf(fmaxf(acc[mi][0][r], acc[mi][1][r]), fmaxf(acc[mi][2][r], acc[mi][3][r]));
#pragma unroll
      for (int s = 1; s < 16; s <<= 1) mx = fmaxf(mx, __shfl_xor(mx, s));
      float e0 = __expf(acc[mi][0][r] - mx), e1 = __expf(acc[mi][1][r] - mx);
      float e2 = __expf(acc[mi][2][r] - mx), e3 = __expf(acc[mi][3][r] - mx);
      float sum = e0 + e1 + e2 + e3;
#pragma unroll
      for (int s = 1; s < 16; s <<= 1) sum += __shfl_xor(sum, s);
      const float inv = 1.f / sum;
      const int i = mi * 16 + lq * 4 + r;
      Qs[i * 64 +  0 + lr] = f2b(e0 * inv);
      Qs[i * 64 + 16 + lr] = f2b(e1 * inv);
      Qs[i * 64 + 32 + lr] = f2b(e2 * inv);
      Qs[i * 64 + 48 + lr] = f2b(e3 * inv);
    }
  }
  __syncthreads();

  f32x4 o_[4][4];
#pragma unroll
  for (int i = 0; i < 4; ++i)
#pragma unroll
    for (int j = 0; j < 4; ++j) o_[i][j] = (f32x4){0.f, 0.f, 0.f, 0.f};

#pragma unroll
  for (int kt = 0; kt < 2; ++kt) {
    bf16x8 pa[4], vv[4];
#pragma unroll
    for (int i = 0; i < 4; ++i) {
      pa[i] = *(const bf16x8*)&Qs[(i * 16 + lr) * 64 + kt * 32 + lq * 8];
      vv[i] = *(const bf16x8*)&Vs[(i * 16 + lr) * 64 + kt * 32 + lq * 8];
    }
#pragma unroll
    for (int mi = 0; mi < 4; ++mi)
#pragma unroll
      for (int ni = 0; ni < 4; ++ni)
        o_[mi][ni] = __builtin_amdgcn_mfma_f32_16x16x32_bf16(pa[mi], vv[ni], o_[mi][ni], 0, 0, 0);
  }

#pragma unroll
  for (int mi = 0; mi < 4; ++mi)
#pragma unroll
    for (int ni = 0; ni < 4; ++ni)
#pragma unroll
      for (int r = 0; r < 4; ++r) {
        const int i = mi * 16 + lq * 4 + r;
        const int d = ni * 16 + lr;
        ctx[((long)i * C_ + c) * E_ + h * 64 + d] = f2b(o_[mi][ni][r]);
      }
}

// ---------------------------------------------------------------- host launch
extern "C" void kernel_launch(void* const* d_in, const int* in_sizes, int n_in,
                              void* d_out, int out_size, void* d_ws, size_t ws_size,
                              hipStream_t stream)
{
  (void)in_sizes; (void)n_in; (void)out_size; (void)ws_size;
  const float* x     = (const float*)d_in[0];
  const float* ln1_s = (const float*)d_in[1];
  const float* ln1_b = (const float*)d_in[2];
  const float* r_wq  = (const float*)d_in[3];
  const float* r_bq  = (const float*)d_in[4];
  const float* r_wk  = (const float*)d_in[5];
  const float* r_bk  = (const float*)d_in[6];
  const float* r_wv  = (const float*)d_in[7];
  const float* r_bv  = (const float*)d_in[8];
  const float* r_wo  = (const float*)d_in[9];
  const float* r_bo  = (const float*)d_in[10];
  const float* ln2_s = (const float*)d_in[11];
  const float* ln2_b = (const float*)d_in[12];
  const float* c_wq  = (const float*)d_in[13];
  const float* c_bq  = (const float*)d_in[14];
  const float* c_wk  = (const float*)d_in[15];
  const float* c_bk  = (const float*)d_in[16];
  const float* c_wv  = (const float*)d_in[17];
  const float* c_bv  = (const float*)d_in[18];
  const float* c_wo  = (const float*)d_in[19];
  const float* c_bo  = (const float*)d_in[20];
  const float* ln3_s = (const float*)d_in[21];
  const float* ln3_b = (const float*)d_in[22];
  const float* f_w1  = (const float*)d_in[23];
  const float* f_b1  = (const float*)d_in[24];
  const float* f_w2  = (const float*)d_in[25];
  const float* f_b2  = (const float*)d_in[26];

  uint8_t* p = (uint8_t*)d_ws;
  auto take = [&p](size_t n) { uint8_t* r = p; p += (n + 255) & ~(size_t)255; return r; };

  uint16_t* wqkv1 = (uint16_t*)take((size_t)3 * E_ * E_ * 2);
  uint16_t* wqkv2 = (uint16_t*)take((size_t)3 * E_ * E_ * 2);
  uint16_t* rwoT  = (uint16_t*)take((size_t)E_ * E_ * 2);
  uint16_t* cwoT  = (uint16_t*)take((size_t)E_ * E_ * 2);
  uint16_t* w1T   = (uint16_t*)take((size_t)E_ * F_ * 2);
  uint16_t* w2T   = (uint16_t*)take((size_t)F_ * E_ * 2);
  uint16_t* hb    = (uint16_t*)take((size_t)NT_ * E_ * 2);
  uint16_t* qkvT  = (uint16_t*)take(3 * HCRD_ * 2);
  uint16_t* qT = qkvT, *kT = qkvT + HCRD_, *vT = qkvT + 2 * HCRD_;
  uint16_t* ctxb  = (uint16_t*)take((size_t)NT_ * E_ * 2);
  uint16_t* apb   = (uint16_t*)take((size_t)H_ * C_ * C_ * 2);
  uint16_t* g     = qkvT;          // alias: stage-3 FFN hidden over dead q/k/v
  float*    awb4  = (float*)ctxb;  // alias: split-K partials dead before ctxb written
  float*    x1    = (float*)d_out; // alias: inter-stage fp32 activation in output buf

  const dim3 tb32(32, 8);
  tcvt8<<<dim3(E_ / 32, E_ / 32, 8), tb32, 0, stream>>>(
      r_wq, r_wk, r_wv, c_wq, c_wk, c_wv, r_wo, c_wo,
      wqkv1 + 0 * E_ * E_, wqkv1 + 1 * E_ * E_, wqkv1 + 2 * E_ * E_,
      wqkv2 + 0 * E_ * E_, wqkv2 + 1 * E_ * E_, wqkv2 + 2 * E_ * E_,
      rwoT, cwoT);
  tcvt<<<dim3(F_ / 32, E_ / 32), tb32, 0, stream>>>(f_w1, w1T, E_, F_);
  tcvt<<<dim3(E_ / 32, F_ / 32), tb32, 0, stream>>>(f_w2, w2T, F_, E_);

  // ---- stage 1: tied-row attention ----
  ln_k<<<NT_ / 4, 256, 0, stream>>>(x, ln1_s, ln1_b, hb);
  gemm128<EP_QKVROW, false><<<dim3(9, 128), 512, 0, stream>>>(
      hb, wqkv1, r_bq, r_bk, r_bv, qkvT, 3 * E_, E_, E_, E_, 0.015625f);
  gemm_bt<EP_AW><<<dim3(8, 2, H_), 256, 0, stream>>>(
      qT, kT, awb4, C_, C_, 1024, R_ * D_, R_ * D_, (long)C_ * R_ * D_, (long)C_ * R_ * D_);
  softmax_k4<<<(H_ * C_) / 4, 256, 0, stream>>>(awb4, apb);
  gemm_bt<EP_CTX><<<dim3((R_ * D_) / 128, 2, H_), 256, 0, stream>>>(
      apb, vT, ctxb, C_, R_ * D_, C_, C_, C_, (long)C_ * C_, (long)R_ * D_ * C_);
  gemm128<EP_F32B, false><<<dim3(3, 128), 512, 0, stream>>>(
      ctxb, rwoT, r_bo, nullptr, nullptr, x1, E_, E_, E_, E_, 1.f);

  // ---- stage 2: column attention ----
  ln_k<<<NT_ / 4, 256, 0, stream>>>(x1, ln2_s, ln2_b, hb);
  gemm128<EP_QKVCOL, true><<<dim3(9, 128), 512, 0, stream>>>(
      hb, wqkv2, c_bq, c_bk, c_bv, qkvT, 3 * E_, E_, E_, E_, 0.125f);
  colattn<<<H_ * C_, 64, 0, stream>>>(qT, kT, vT, ctxb);
  gemm128<EP_F32B, false><<<dim3(3, 128), 512, 0, stream>>>(
      ctxb, cwoT, c_bo, nullptr, nullptr, x1, E_, E_, E_, E_, 1.f);

  // ---- stage 3: FFN ----
  ln_k<<<NT_ / 4, 256, 0, stream>>>(x1, ln3_s, ln3_b, hb);
  gemm128<EP_GELU, false><<<dim3(12, 128), 512, 0, stream>>>(
      hb, w1T, f_b1, nullptr, nullptr, g, F_, E_, E_, E_, 1.f);
  gemm128<EP_F32B, false><<<dim3(3, 128), 512, 0, stream>>>(
      g, w2T, f_b2, nullptr, nullptr, d_out, E_, F_, F_, F_, 1.f);
}

// Round 18
// 511.269 us; speedup vs baseline: 4.3390x; 1.0102x over previous
//
#include <hip/hip_runtime.h>
#include <hip/hip_bf16.h>
#include <stdint.h>
#include <stddef.h>

#define R_ 64
#define C_ 256
#define E_ 768
#define H_ 12
#define F_ 3072
#define D_ 64
#define NT_ (R_*C_)   // 16384 tokens
#define HCRD_ ((size_t)H_*C_*R_*D_)

typedef float f32x4 __attribute__((ext_vector_type(4)));
typedef __bf16 bf16x8 __attribute__((ext_vector_type(8)));
typedef unsigned short us4 __attribute__((ext_vector_type(4)));
typedef unsigned short us8 __attribute__((ext_vector_type(8)));

typedef __attribute__((address_space(3))) uint32_t lds_u32;
typedef __attribute__((address_space(1))) uint32_t glb_u32;

__device__ __forceinline__ void gld16(const uint16_t* g, uint16_t* l) {
  __builtin_amdgcn_global_load_lds((const glb_u32*)g, (lds_u32*)l, 16, 0, 0);
}

__device__ __forceinline__ uint16_t f2b(float f) { // fp32 -> bf16, native cvt (RNE)
  __bf16 h = (__bf16)f;
  return *(uint16_t*)&h;
}
__device__ __forceinline__ float b2f(uint16_t u) {
  return __uint_as_float((uint32_t)u << 16);
}

#define BAR      { asm volatile("s_barrier" ::: "memory"); }
#define VMW0     { asm volatile("s_waitcnt vmcnt(0)" ::: "memory"); }

enum { EP_F32B = 0, EP_GELU = 1, EP_AW = 2, EP_CTX = 3, EP_QKVROW = 4, EP_QKVCOL = 5, EP_X1 = 6 };

// ================================================================ 128x256 GEMM, BK=32 (all EPs)
// Verified r14/r17 operating point: 8 waves (2M x 4N), wave tile 64x64, acc[4][4]
// (VGPR 56, no spill) -> TWO blocks/CU co-resident (m114 latency absorption).
// LDS 64KB: K-loop 48KB (A 8KB x2 + B 16KB x2); epilogue slab 8 waves x 8KB.
// EP_X1: bias -> bf16 inter-stage activation (no residual in this model) via slab.
template<int EP, bool PERM>
__global__ __launch_bounds__(512, 4)
void gemm128(const uint16_t* __restrict__ A, const uint16_t* __restrict__ B,
             const float* __restrict__ bias, const float* __restrict__ biasK,
             const float* __restrict__ biasV, void* __restrict__ out,
             int N, int K, int lda, int ldb, float scale)
{
  __shared__ uint16_t lds[32768];   // 64KB
  const int tid  = threadIdx.x;
  const int wave = tid >> 6, lane = tid & 63;
  const int wm = wave >> 2, wn = wave & 3;
  const int lr = lane & 15, lq = lane >> 4;

  // XCD-chunked bijective block swizzle (total blocks %8==0 in all uses)
  const int lin = blockIdx.x + gridDim.x * blockIdx.y;
  const int q8 = (gridDim.x * gridDim.y) >> 3;
  const int wid = (lin & 7) * q8 + (lin >> 3);
  const int bx = wid % gridDim.x, by = wid / gridDim.x;
  const long bm = (long)by * 128, bn = (long)bx * 256;

  // staging: A 8KB/tile (512 slots, 1/thread), B 16KB/tile (1024 slots, 2/thread)
  const int r0 = tid >> 2;                                 // 0..127
  const int c8 = (((tid & 3) ^ ((r0 >> 1) & 3)) << 3);     // both-sides XOR swizzle
  long am = bm + r0;
  if constexpr (PERM) am = ((am & 63) << 8) | (am >> 6);   // token (m&63)*256 + m>>6
  const uint16_t* aS  = A + am * (long)lda + c8;
  const uint16_t* bS0 = B + (bn + r0) * (long)ldb + c8;
  const uint16_t* bS1 = B + (bn + r0 + 128) * (long)ldb + c8;

  auto stage = [&](int u) {   // 3 gld16/thread per tile
    const int b = u & 1, kb = u << 5;
    gld16(aS  + kb, &lds[b * 4096 + tid * 8]);
    gld16(bS0 + kb, &lds[8192 + b * 8192 + tid * 8]);
    gld16(bS1 + kb, &lds[8192 + b * 8192 + (tid + 512) * 8]);
  };
  auto rdoff = [&](int row) { return row * 32 + ((lq ^ ((row >> 1) & 3)) << 3); };

  f32x4 acc[4][4];
#pragma unroll
  for (int i = 0; i < 4; ++i)
#pragma unroll
    for (int j = 0; j < 4; ++j) acc[i][j] = (f32x4){0.f, 0.f, 0.f, 0.f};

  const int nt = K >> 5;   // 24 or 96
  stage(0);
  VMW0; BAR;

  for (int t = 0; t < nt; ++t) {
    const int b = t & 1;
    if (t + 1 < nt) stage(t + 1);
    const uint16_t* Ab = &lds[b * 4096];
    const uint16_t* Bb = &lds[8192 + b * 8192];
    bf16x8 af[4], bf[4];
#pragma unroll
    for (int i = 0; i < 4; ++i) {
      af[i] = *(const bf16x8*)&Ab[rdoff(wm * 64 + i * 16 + lr)];
      bf[i] = *(const bf16x8*)&Bb[rdoff(wn * 64 + i * 16 + lr)];
    }
#pragma unroll
    for (int mi = 0; mi < 4; ++mi)
#pragma unroll
      for (int ni = 0; ni < 4; ++ni)
        acc[mi][ni] = __builtin_amdgcn_mfma_f32_16x16x32_bf16(af[mi], bf[ni], acc[mi][ni], 0, 0, 0);
    if (t + 1 < nt) { VMW0; BAR; }
  }
  __syncthreads();

  // ------------------------------------------------------------- epilogue (one 64x64/wave)
  if constexpr (EP == EP_F32B) {
#pragma unroll
    for (int mi = 0; mi < 4; ++mi)
#pragma unroll
      for (int ni = 0; ni < 4; ++ni)
#pragma unroll
        for (int r = 0; r < 4; ++r) {
          const long row = bm + wm * 64 + mi * 16 + lq * 4 + r;
          const long col = bn + wn * 64 + ni * 16 + lr;
          ((float*)out)[row * N + col] = acc[mi][ni][r] + bias[col];
        }
  } else {
    uint16_t* slab = &lds[wave * 4096];   // wave-private 8KB
    const long colb = bn + wn * 64;
    const long m0 = bm + wm * 64;
    constexpr bool PLAIN = (EP == EP_GELU || EP == EP_X1);   // row-major bf16 out
    int grp = 0; long cc0 = colb;
    const float* bb = bias;
    if constexpr (!PLAIN) {
      grp = colb >= 1536 ? 2 : (colb >= 768 ? 1 : 0);
      cc0 = colb - (long)grp * 768;
      bb = grp == 0 ? bias : (grp == 1 ? biasK : biasV);
    }
    const bool tr = (!PLAIN) && (grp == 2);   // V dumps transposed [d][tok]
#pragma unroll
    for (int mi = 0; mi < 4; ++mi)
#pragma unroll
      for (int ni = 0; ni < 4; ++ni)
#pragma unroll
        for (int r = 0; r < 4; ++r) {
          const int lrow = mi * 16 + lq * 4 + r;
          const int lcol = ni * 16 + lr;
          float val;
          if constexpr (EP == EP_GELU) {
            const float t = acc[mi][ni][r] + bias[colb + lcol];
            const float u = 0.7978845608028654f * (t + 0.044715f * t * t * t);
            const float e2 = __expf(2.f * u);
            val = 0.5f * t * (2.f - 2.f / (e2 + 1.f));
          } else if constexpr (EP == EP_X1) {
            val = acc[mi][ni][r] + bias[colb + lcol];
          } else {
            val = acc[mi][ni][r] + bb[cc0 + lcol];
            if (grp == 0) val *= scale;
          }
          const int sr = tr ? lcol : lrow;
          const int sc = tr ? lrow : lcol;
          const int psc = (sc & 7) | ((((sc >> 3) ^ (sr & 7))) << 3);
          slab[sr * 64 + psc] = f2b(val);
        }
    // wave-private slab: ds_write -> ds_read same wave, no barrier needed
    uint16_t* o16 = (uint16_t*)out;
    long obase, rstride;
    if constexpr (PLAIN) {
      obase = m0 * (long)N + colb; rstride = N;
    } else {
      const long h = cc0 >> 6;
      if constexpr (EP == EP_QKVROW) {   // tile rows = tokens (fixed r, c varies)
        const long rr2 = m0 >> 8, c0 = m0 & 255;
        if (grp < 2) { obase = (size_t)grp * HCRD_ + ((h * C_ + c0) * R_ + rr2) * D_; rstride = R_ * D_; }
        else         { obase = 2 * HCRD_ + ((h * R_ + rr2) * D_) * C_ + c0;           rstride = C_; }
      } else {                           // QKVCOL: tile rows = r (fixed c)
        const long cq = m0 >> 6;
        if (grp < 2) { obase = (size_t)grp * HCRD_ + ((h * C_ + cq) * R_) * D_; rstride = D_; }
        else         { obase = 2 * HCRD_ + ((h * C_ + cq) * D_) * R_;           rstride = R_; }
      }
    }
    const int rl = lane >> 3, chn = lane & 7;
#pragma unroll
    for (int pp = 0; pp < 8; ++pp) {
      const int srow = pp * 8 + rl;
      const int pch = chn ^ (srow & 7);
      us8 wv = *(const us8*)&slab[srow * 64 + pch * 8];
      *(us8*)(o16 + obase + (long)srow * rstride + chn * 8) = wv;
    }
  }
}

// ================================================================ 128x128 GEMM (AW / CTX)
template<int EP>
__global__ __launch_bounds__(256)
void gemm_bt(const uint16_t* __restrict__ A, const uint16_t* __restrict__ B,
             void* __restrict__ out,
             int M, int N, int K, int lda, int ldb, long sAz, long sBz)
{
  __shared__ uint16_t As[2][4096];
  __shared__ uint16_t Bs[2][4096];
  const int tid  = threadIdx.x;
  const int wave = tid >> 6, lane = tid & 63;
  const int z = blockIdx.z;

  const long bm = (long)blockIdx.y * 128;
  int kc = 0; long bnb = blockIdx.x;
  if constexpr (EP == EP_AW) { kc = blockIdx.x & 3; bnb = blockIdx.x >> 2; }
  const long bn = bnb * 128;
  const int wr = (wave >> 1) * 64;
  const int wc = (wave & 1) * 64;
  const int lr = lane & 15;
  const int lq = lane >> 4;

  const int t0 = tid, t1 = tid + 256;
  const int ar0 = t0 >> 2, ar1 = t1 >> 2;
  const int ac0 = (((t0 & 3) ^ ((ar0 >> 1) & 3)) * 8);
  const int ac1 = (((t1 & 3) ^ ((ar1 >> 1) & 3)) * 8);

  const uint16_t* a0p = A + (long)z * sAz + (bm + ar0) * (long)lda + (long)kc * 1024;
  const uint16_t* a1p = A + (long)z * sAz + (bm + ar1) * (long)lda + (long)kc * 1024;
  const uint16_t* b0p = B + (long)z * sBz + (bn + ar0) * (long)ldb + (long)kc * 1024;
  const uint16_t* b1p = B + (long)z * sBz + (bn + ar1) * (long)ldb + (long)kc * 1024;

  auto STAGE = [&](int bi, int kt) {
    gld16(a0p + kt + ac0, &As[bi][t0 * 8]);
    gld16(a1p + kt + ac1, &As[bi][t1 * 8]);
    gld16(b0p + kt + ac0, &Bs[bi][t0 * 8]);
    gld16(b1p + kt + ac1, &Bs[bi][t1 * 8]);
  };

  int apos[4], bpos[4];
#pragma unroll
  for (int i = 0; i < 4; ++i) {
    const int ra = wr + i * 16 + lr;
    const int rb = wc + i * 16 + lr;
    apos[i] = ra * 32 + (lq ^ ((ra >> 1) & 3)) * 8;
    bpos[i] = rb * 32 + (lq ^ ((rb >> 1) & 3)) * 8;
  }

  f32x4 acc[4][4];
#pragma unroll
  for (int i = 0; i < 4; ++i)
#pragma unroll
    for (int j = 0; j < 4; ++j) acc[i][j] = (f32x4){0.f, 0.f, 0.f, 0.f};

  const int nt = K >> 5;
  STAGE(0, 0);
  VMW0; BAR;

  for (int t = 0; t < nt; ++t) {
    const int b = t & 1;
    if (t + 1 < nt) STAGE(b ^ 1, (t + 1) << 5);
    bf16x8 af[4], bfm[4];
#pragma unroll
    for (int i = 0; i < 4; ++i) {
      af[i]  = *(const bf16x8*)&As[b][apos[i]];
      bfm[i] = *(const bf16x8*)&Bs[b][bpos[i]];
    }
#pragma unroll
    for (int mi = 0; mi < 4; ++mi)
#pragma unroll
      for (int ni = 0; ni < 4; ++ni)
        acc[mi][ni] = __builtin_amdgcn_mfma_f32_16x16x32_bf16(af[mi], bfm[ni], acc[mi][ni], 0, 0, 0);
    if (t + 1 < nt) { VMW0; BAR; }
  }

#pragma unroll
  for (int mi = 0; mi < 4; ++mi)
#pragma unroll
    for (int ni = 0; ni < 4; ++ni)
#pragma unroll
      for (int r = 0; r < 4; ++r) {
        const long row = bm + wr + mi * 16 + lq * 4 + r;
        const long col = bn + wc + ni * 16 + lr;
        if constexpr (EP == EP_AW) {
          ((float*)out)[((long)(z * 4 + kc) * M + row) * N + col] = acc[mi][ni][r];
        } else {  // EP_CTX
          ((uint16_t*)out)[((col >> 6) * C_ + row) * E_ + (long)z * 64 + (col & 63)] =
              f2b(acc[mi][ni][r]);
        }
      }
}

// ------------------------------------------- LayerNorm (fp32 in -> bf16 out)
__global__ __launch_bounds__(256)
void ln_k(const float* __restrict__ x, const float* __restrict__ s, const float* __restrict__ b,
          uint16_t* __restrict__ out)
{
  const int wave = threadIdx.x >> 6, lane = threadIdx.x & 63;
  const long row = (long)blockIdx.x * 4 + wave;
  const float* xr = x + row * E_;
  f32x4 v[3];
  float sum = 0.f, sq = 0.f;
#pragma unroll
  for (int i = 0; i < 3; ++i) {
    v[i] = *(const f32x4*)(xr + (i * 64 + lane) * 4);
#pragma unroll
    for (int j = 0; j < 4; ++j) { sum += v[i][j]; sq += v[i][j] * v[i][j]; }
  }
#pragma unroll
  for (int m = 1; m < 64; m <<= 1) { sum += __shfl_xor(sum, m); sq += __shfl_xor(sq, m); }
  const float mu = sum * (1.f / E_);
  const float var = sq * (1.f / E_) - mu * mu;
  const float rs = rsqrtf(var + 1e-6f);
  uint16_t* orow = out + row * E_;
#pragma unroll
  for (int i = 0; i < 3; ++i) {
    const int e0 = (i * 64 + lane) * 4;
    us4 o;
#pragma unroll
    for (int j = 0; j < 4; ++j) o[j] = f2b((v[i][j] - mu) * rs * s[e0 + j] + b[e0 + j]);
    *(us4*)(orow + e0) = o;
  }
}

// ------------------------------------------- LayerNorm (bf16 in -> bf16 out)
__global__ __launch_bounds__(256)
void ln_b(const uint16_t* __restrict__ x, const float* __restrict__ s, const float* __restrict__ b,
          uint16_t* __restrict__ out)
{
  const int wave = threadIdx.x >> 6, lane = threadIdx.x & 63;
  const long row = (long)blockIdx.x * 4 + wave;
  const uint16_t* xr = x + row * E_;
  float v[12];
  float sum = 0.f, sq = 0.f;
#pragma unroll
  for (int i = 0; i < 3; ++i) {
    us4 raw = *(const us4*)(xr + (i * 64 + lane) * 4);
#pragma unroll
    for (int j = 0; j < 4; ++j) {
      const float f = b2f(raw[j]);
      v[i * 4 + j] = f; sum += f; sq += f * f;
    }
  }
#pragma unroll
  for (int m = 1; m < 64; m <<= 1) { sum += __shfl_xor(sum, m); sq += __shfl_xor(sq, m); }
  const float mu = sum * (1.f / E_);
  const float var = sq * (1.f / E_) - mu * mu;
  const float rs = rsqrtf(var + 1e-6f);
  uint16_t* orow = out + row * E_;
#pragma unroll
  for (int i = 0; i < 3; ++i) {
    const int e0 = (i * 64 + lane) * 4;
    us4 o;
#pragma unroll
    for (int j = 0; j < 4; ++j) o[j] = f2b((v[i * 4 + j] - mu) * rs * s[e0 + j] + b[e0 + j]);
    *(us4*)(orow + e0) = o;
  }
}

// ------------------------------------------------ softmax over 256, summing 4 split-K partials
__global__ __launch_bounds__(256)
void softmax_k4(const float* __restrict__ aw4, uint16_t* __restrict__ ap)
{
  const int wave = threadIdx.x >> 6, lane = threadIdx.x & 63;
  const long row = (long)blockIdx.x * 4 + wave;
  const long h = row >> 8, i = row & 255;
  f32x4 v = (f32x4){0.f, 0.f, 0.f, 0.f};
#pragma unroll
  for (int kc = 0; kc < 4; ++kc) {
    f32x4 t = *(const f32x4*)(aw4 + (((h * 4 + kc) * C_ + i) * C_) + lane * 4);
#pragma unroll
    for (int j = 0; j < 4; ++j) v[j] += t[j];
  }
  float m = fmaxf(fmaxf(v[0], v[1]), fmaxf(v[2], v[3]));
#pragma unroll
  for (int k = 1; k < 64; k <<= 1) m = fmaxf(m, __shfl_xor(m, k));
  f32x4 e; float s = 0.f;
#pragma unroll
  for (int j = 0; j < 4; ++j) { e[j] = __expf(v[j] - m); s += e[j]; }
#pragma unroll
  for (int k = 1; k < 64; k <<= 1) s += __shfl_xor(s, k);
  const float inv = 1.f / s;
  us4 o;
#pragma unroll
  for (int j = 0; j < 4; ++j) o[j] = f2b(e[j] * inv);
  *(us4*)(ap + row * C_ + lane * 4) = o;
}

// ------------------------------------- weight transpose fp32->bf16: single (K,N)->(N,K) kernel
__global__ __launch_bounds__(256)
void tcvt(const float* __restrict__ in, uint16_t* __restrict__ out, int K, int N)
{
  __shared__ float t[32][33];
  const int tx = threadIdx.x, ty = threadIdx.y;   // block (32,8)
  const long k0 = (long)blockIdx.y * 32, n0 = (long)blockIdx.x * 32;
  for (int i = ty; i < 32; i += 8) t[i][tx] = in[(k0 + i) * N + n0 + tx];
  __syncthreads();
  for (int i = ty; i < 32; i += 8) out[(n0 + i) * K + k0 + tx] = f2b(t[tx][i]);
}

// ---------------------- batched 768x768 transpose for the 8 E x E weights (1 launch, z=0..7)
__global__ __launch_bounds__(256)
void tcvt8(const float* a0, const float* a1, const float* a2, const float* a3,
           const float* a4, const float* a5, const float* a6, const float* a7,
           uint16_t* o0, uint16_t* o1, uint16_t* o2, uint16_t* o3,
           uint16_t* o4, uint16_t* o5, uint16_t* o6, uint16_t* o7)
{
  __shared__ float t[32][33];
  const float* in; uint16_t* out;
  switch (blockIdx.z) {
    case 0: in = a0; out = o0; break;
    case 1: in = a1; out = o1; break;
    case 2: in = a2; out = o2; break;
    case 3: in = a3; out = o3; break;
    case 4: in = a4; out = o4; break;
    case 5: in = a5; out = o5; break;
    case 6: in = a6; out = o6; break;
    default: in = a7; out = o7; break;
  }
  const int tx = threadIdx.x, ty = threadIdx.y;   // block (32,8)
  const long k0 = (long)blockIdx.y * 32, n0 = (long)blockIdx.x * 32;
  for (int i = ty; i < 32; i += 8) t[i][tx] = in[(k0 + i) * E_ + n0 + tx];
  __syncthreads();
  for (int i = ty; i < 32; i += 8) out[(n0 + i) * E_ + k0 + tx] = f2b(t[tx][i]);
}

// ---------------------------------------------------------------- fused column attention
__global__ __launch_bounds__(64)
void colattn(const uint16_t* __restrict__ q, const uint16_t* __restrict__ k,
             const uint16_t* __restrict__ v, uint16_t* __restrict__ ctx)
{
  __shared__ uint16_t Qs[64 * 64];
  __shared__ uint16_t Ks[64 * 64];
  __shared__ uint16_t Vs[64 * 64];
  const int hc = blockIdx.x;
  const int h = hc >> 8, c = hc & 255;
  const int lane = threadIdx.x;
  const uint16_t* qb = q + (long)hc * (R_ * D_);
  const uint16_t* kb = k + (long)hc * (R_ * D_);
  const uint16_t* vb = v + (long)hc * (D_ * R_);
#pragma unroll
  for (int it = 0; it < 8; ++it) {
    const int o = (it * 64 + lane) * 8;
    gld16(qb + o, &Qs[o]);
    gld16(kb + o, &Ks[o]);
    gld16(vb + o, &Vs[o]);
  }
  asm volatile("s_waitcnt vmcnt(0)" ::: "memory");
  __builtin_amdgcn_sched_barrier(0);

  const int lr = lane & 15, lq = lane >> 4;
  f32x4 acc[4][4];
#pragma unroll
  for (int i = 0; i < 4; ++i)
#pragma unroll
    for (int j = 0; j < 4; ++j) acc[i][j] = (f32x4){0.f, 0.f, 0.f, 0.f};

#pragma unroll
  for (int kt = 0; kt < 2; ++kt) {
    bf16x8 af[4], bfm[4];
#pragma unroll
    for (int i = 0; i < 4; ++i) {
      af[i]  = *(const bf16x8*)&Qs[(i * 16 + lr) * 64 + kt * 32 + lq * 8];
      bfm[i] = *(const bf16x8*)&Ks[(i * 16 + lr) * 64 + kt * 32 + lq * 8];
    }
#pragma unroll
    for (int mi = 0; mi < 4; ++mi)
#pragma unroll
      for (int ni = 0; ni < 4; ++ni)
        acc[mi][ni] = __builtin_amdgcn_mfma_f32_16x16x32_bf16(af[mi], bfm[ni], acc[mi][ni], 0, 0, 0);
  }

#pragma unroll
  for (int mi = 0; mi < 4; ++mi) {
#pragma unroll
    for (int r = 0; r < 4; ++r) {
      float mx = fmaxf(fmaxf(acc[mi][0][r], acc[mi][1][r]), fmaxf(acc[mi][2][r], acc[mi][3][r]));
#pragma unroll
      for (int s = 1; s < 16; s <<= 1) mx = fmaxf(mx, __shfl_xor(mx, s));
      float e0 = __expf(acc[mi][0][r] - mx), e1 = __expf(acc[mi][1][r] - mx);
      float e2 = __expf(acc[mi][2][r] - mx), e3 = __expf(acc[mi][3][r] - mx);
      float sum = e0 + e1 + e2 + e3;
#pragma unroll
      for (int s = 1; s < 16; s <<= 1) sum += __shfl_xor(sum, s);
      const float inv = 1.f / sum;
      const int i = mi * 16 + lq * 4 + r;
      Qs[i * 64 +  0 + lr] = f2b(e0 * inv);
      Qs[i * 64 + 16 + lr] = f2b(e1 * inv);
      Qs[i * 64 + 32 + lr] = f2b(e2 * inv);
      Qs[i * 64 + 48 + lr] = f2b(e3 * inv);
    }
  }
  __syncthreads();

  f32x4 o_[4][4];
#pragma unroll
  for (int i = 0; i < 4; ++i)
#pragma unroll
    for (int j = 0; j < 4; ++j) o_[i][j] = (f32x4){0.f, 0.f, 0.f, 0.f};

#pragma unroll
  for (int kt = 0; kt < 2; ++kt) {
    bf16x8 pa[4], vv[4];
#pragma unroll
    for (int i = 0; i < 4; ++i) {
      pa[i] = *(const bf16x8*)&Qs[(i * 16 + lr) * 64 + kt * 32 + lq * 8];
      vv[i] = *(const bf16x8*)&Vs[(i * 16 + lr) * 64 + kt * 32 + lq * 8];
    }
#pragma unroll
    for (int mi = 0; mi < 4; ++mi)
#pragma unroll
      for (int ni = 0; ni < 4; ++ni)
        o_[mi][ni] = __builtin_amdgcn_mfma_f32_16x16x32_bf16(pa[mi], vv[ni], o_[mi][ni], 0, 0, 0);
  }

#pragma unroll
  for (int mi = 0; mi < 4; ++mi)
#pragma unroll
    for (int ni = 0; ni < 4; ++ni)
#pragma unroll
      for (int r = 0; r < 4; ++r) {
        const int i = mi * 16 + lq * 4 + r;
        const int d = ni * 16 + lr;
        ctx[((long)i * C_ + c) * E_ + h * 64 + d] = f2b(o_[mi][ni][r]);
      }
}

// ---------------------------------------------------------------- host launch
extern "C" void kernel_launch(void* const* d_in, const int* in_sizes, int n_in,
                              void* d_out, int out_size, void* d_ws, size_t ws_size,
                              hipStream_t stream)
{
  (void)in_sizes; (void)n_in; (void)out_size; (void)ws_size;
  const float* x     = (const float*)d_in[0];
  const float* ln1_s = (const float*)d_in[1];
  const float* ln1_b = (const float*)d_in[2];
  const float* r_wq  = (const float*)d_in[3];
  const float* r_bq  = (const float*)d_in[4];
  const float* r_wk  = (const float*)d_in[5];
  const float* r_bk  = (const float*)d_in[6];
  const float* r_wv  = (const float*)d_in[7];
  const float* r_bv  = (const float*)d_in[8];
  const float* r_wo  = (const float*)d_in[9];
  const float* r_bo  = (const float*)d_in[10];
  const float* ln2_s = (const float*)d_in[11];
  const float* ln2_b = (const float*)d_in[12];
  const float* c_wq  = (const float*)d_in[13];
  const float* c_bq  = (const float*)d_in[14];
  const float* c_wk  = (const float*)d_in[15];
  const float* c_bk  = (const float*)d_in[16];
  const float* c_wv  = (const float*)d_in[17];
  const float* c_bv  = (const float*)d_in[18];
  const float* c_wo  = (const float*)d_in[19];
  const float* c_bo  = (const float*)d_in[20];
  const float* ln3_s = (const float*)d_in[21];
  const float* ln3_b = (const float*)d_in[22];
  const float* f_w1  = (const float*)d_in[23];
  const float* f_b1  = (const float*)d_in[24];
  const float* f_w2  = (const float*)d_in[25];
  const float* f_b2  = (const float*)d_in[26];

  uint8_t* p = (uint8_t*)d_ws;
  auto take = [&p](size_t n) { uint8_t* r = p; p += (n + 255) & ~(size_t)255; return r; };

  uint16_t* wqkv1 = (uint16_t*)take((size_t)3 * E_ * E_ * 2);
  uint16_t* wqkv2 = (uint16_t*)take((size_t)3 * E_ * E_ * 2);
  uint16_t* rwoT  = (uint16_t*)take((size_t)E_ * E_ * 2);
  uint16_t* cwoT  = (uint16_t*)take((size_t)E_ * E_ * 2);
  uint16_t* w1T   = (uint16_t*)take((size_t)E_ * F_ * 2);
  uint16_t* w2T   = (uint16_t*)take((size_t)F_ * E_ * 2);
  uint16_t* hb    = (uint16_t*)take((size_t)NT_ * E_ * 2);
  uint16_t* qkvT  = (uint16_t*)take(3 * HCRD_ * 2);
  uint16_t* qT = qkvT, *kT = qkvT + HCRD_, *vT = qkvT + 2 * HCRD_;
  uint16_t* ctxb  = (uint16_t*)take((size_t)NT_ * E_ * 2);
  uint16_t* apb   = (uint16_t*)take((size_t)H_ * C_ * C_ * 2);
  uint16_t* g     = qkvT;          // alias: stage-3 FFN hidden over dead q/k/v
  float*    awb4  = (float*)ctxb;  // alias: split-K partials dead before ctxb written
  // x1b (bf16 inter-stage activation, 25.2 MB) aliases qT: q is dead once AW (stage 1)
  // or colattn (stage 2) completes, and x1b is consumed by the next LN before QKV/FFN
  // overwrite qkvT. No residual connections in this model, so x1's lifetime is short.
  uint16_t* x1b   = qT;

  const dim3 tb32(32, 8);
  tcvt8<<<dim3(E_ / 32, E_ / 32, 8), tb32, 0, stream>>>(
      r_wq, r_wk, r_wv, c_wq, c_wk, c_wv, r_wo, c_wo,
      wqkv1 + 0 * E_ * E_, wqkv1 + 1 * E_ * E_, wqkv1 + 2 * E_ * E_,
      wqkv2 + 0 * E_ * E_, wqkv2 + 1 * E_ * E_, wqkv2 + 2 * E_ * E_,
      rwoT, cwoT);
  tcvt<<<dim3(F_ / 32, E_ / 32), tb32, 0, stream>>>(f_w1, w1T, E_, F_);
  tcvt<<<dim3(E_ / 32, F_ / 32), tb32, 0, stream>>>(f_w2, w2T, F_, E_);

  // ---- stage 1: tied-row attention ----
  ln_k<<<NT_ / 4, 256, 0, stream>>>(x, ln1_s, ln1_b, hb);
  gemm128<EP_QKVROW, false><<<dim3(9, 128), 512, 0, stream>>>(
      hb, wqkv1, r_bq, r_bk, r_bv, qkvT, 3 * E_, E_, E_, E_, 0.015625f);
  gemm_bt<EP_AW><<<dim3(8, 2, H_), 256, 0, stream>>>(
      qT, kT, awb4, C_, C_, 1024, R_ * D_, R_ * D_, (long)C_ * R_ * D_, (long)C_ * R_ * D_);
  softmax_k4<<<(H_ * C_) / 4, 256, 0, stream>>>(awb4, apb);
  gemm_bt<EP_CTX><<<dim3((R_ * D_) / 128, 2, H_), 256, 0, stream>>>(
      apb, vT, ctxb, C_, R_ * D_, C_, C_, C_, (long)C_ * C_, (long)R_ * D_ * C_);
  gemm128<EP_X1, false><<<dim3(3, 128), 512, 0, stream>>>(
      ctxb, rwoT, r_bo, nullptr, nullptr, x1b, E_, E_, E_, E_, 1.f);

  // ---- stage 2: column attention ----
  ln_b<<<NT_ / 4, 256, 0, stream>>>(x1b, ln2_s, ln2_b, hb);
  gemm128<EP_QKVCOL, true><<<dim3(9, 128), 512, 0, stream>>>(
      hb, wqkv2, c_bq, c_bk, c_bv, qkvT, 3 * E_, E_, E_, E_, 0.125f);
  colattn<<<H_ * C_, 64, 0, stream>>>(qT, kT, vT, ctxb);
  gemm128<EP_X1, false><<<dim3(3, 128), 512, 0, stream>>>(
      ctxb, cwoT, c_bo, nullptr, nullptr, x1b, E_, E_, E_, E_, 1.f);

  // ---- stage 3: FFN ----
  ln_b<<<NT_ / 4, 256, 0, stream>>>(x1b, ln3_s, ln3_b, hb);
  gemm128<EP_GELU, false><<<dim3(12, 128), 512, 0, stream>>>(
      hb, w1T, f_b1, nullptr, nullptr, g, F_, E_, E_, E_, 1.f);
  gemm128<EP_F32B, false><<<dim3(3, 128), 512, 0, stream>>>(
      g, w2T, f_b2, nullptr, nullptr, d_out, E_, F_, F_, F_, 1.f);
}